// Round 8
// baseline (393.771 us; speedup 1.0000x reference)
//
#include <hip/hip_runtime.h>
#include <stdint.h>

#define D_DIM 4096
#define O_DIM 4096
#define M_DIM 8192
#define SCALE_F 2.0f
#define BK 32
#define NKT 128  // D_DIM / BK

typedef __attribute__((ext_vector_type(4))) float f32x4;
typedef __attribute__((ext_vector_type(8))) __bf16 bf16x8;
typedef __attribute__((ext_vector_type(8))) unsigned short u16x8;

__device__ __forceinline__ unsigned short f32_to_bf16_bits(float f) {
    union { float f; uint32_t u; } v; v.f = f;
    return (unsigned short)((v.u + 0x7FFFu + ((v.u >> 16) & 1u)) >> 16);
}

__device__ __forceinline__ float dot4(f32x4 a, f32x4 b) {
    return fmaf(a.x, b.x, fmaf(a.y, b.y, fmaf(a.z, b.z, a.w * b.w)));
}

// swizzle involution on byte offsets within a 16 KiB [256 rows][64 B] tile:
// XOR bits 4-6 with bits 7-9. Verified: SQ_LDS_BANK_CONFLICT == 0 (rounds 3-6).
__device__ __forceinline__ int swz(int b) { return b ^ (((b >> 7) & 7) << 4); }

// ---------------- Kernel 1: f32 -> bf16 convert (W_base) ----------------
__global__ __launch_bounds__(256) void convert_bf16_kernel(const float* __restrict__ src,
                                                           unsigned short* __restrict__ dst,
                                                           int n4) {
    int stride = gridDim.x * blockDim.x;
    for (int i = blockIdx.x * blockDim.x + threadIdx.x; i < n4; i += stride) {
        f32x4 v = ((const f32x4*)src)[i];
        ushort4 o;
        o.x = f32_to_bf16_bits(v.x);
        o.y = f32_to_bf16_bits(v.y);
        o.z = f32_to_bf16_bits(v.z);
        o.w = f32_to_bf16_bits(v.w);
        ((ushort4*)dst)[i] = o;
    }
}

// ---------------- Kernel 2a: partial Y + fused x->bf16 convert ----------------
// grid (64 token-tiles of 128, 8 D-splits), 256 threads. 4 tokens per thread ->
// W-row LDS reads amortize 4x; LDS-read traffic 4.3 GB -> 1.8 GB.
__global__ __launch_bounds__(256) void partial_mixed_kernel(const float* __restrict__ x,
                                                            const float* __restrict__ A_w,
                                                            const float* __restrict__ router_w,
                                                            unsigned short* __restrict__ xbf,
                                                            float* __restrict__ ypart) {
    __shared__ __align__(16) float Xc[128][132];  // 67.6 KiB
    __shared__ __align__(16) float Wc[24][132];   // 12.4 KiB  (80 KiB -> 2 blocks/CU)

    const int tid = threadIdx.x;
    const int t0 = blockIdx.x * 128;
    const int d0 = blockIdx.y * 512;

    const int tg = tid >> 3;  // 0..31; thread owns tokens tg, tg+32, tg+64, tg+96
    const int og = tid & 7;   // outs og*3..og*3+2
    float acc[4][3];
    #pragma unroll
    for (int ti = 0; ti < 4; ++ti)
        #pragma unroll
        for (int wi = 0; wi < 3; ++wi) acc[ti][wi] = 0.f;

    for (int sub = 0; sub < 4; ++sub) {
        const int dbase = d0 + sub * 128;
        __syncthreads();
        // stage Xc: 128x128 f32 = 4096 float4, 16 per thread; fused xbf convert
        #pragma unroll
        for (int i = 0; i < 16; ++i) {
            int idx = i * 256 + tid;
            int t = idx >> 5, dq = idx & 31;
            f32x4 v = *(const f32x4*)&x[(size_t)(t0 + t) * D_DIM + dbase + dq * 4];
            *(f32x4*)&Xc[t][dq * 4] = v;
            ushort4 o;
            o.x = f32_to_bf16_bits(v.x);
            o.y = f32_to_bf16_bits(v.y);
            o.z = f32_to_bf16_bits(v.z);
            o.w = f32_to_bf16_bits(v.w);
            *(ushort4*)&xbf[(size_t)(t0 + t) * D_DIM + dbase + dq * 4] = o;
        }
        // stage Wc: 24x128 f32 = 768 float4, 3 per thread
        #pragma unroll
        for (int i = 0; i < 3; ++i) {
            int idx = i * 256 + tid;
            int r = idx >> 5, dq = idx & 31;
            const float* src = (r < 16) ? (A_w + (size_t)r * D_DIM)
                                        : (router_w + (size_t)(r - 16) * D_DIM);
            *(f32x4*)&Wc[r][dq * 4] = *(const f32x4*)&src[dbase + dq * 4];
        }
        __syncthreads();
        #pragma unroll
        for (int dq = 0; dq < 32; ++dq) {
            f32x4 w0 = *(const f32x4*)&Wc[og * 3 + 0][dq * 4];
            f32x4 w1 = *(const f32x4*)&Wc[og * 3 + 1][dq * 4];
            f32x4 w2 = *(const f32x4*)&Wc[og * 3 + 2][dq * 4];
            #pragma unroll
            for (int ti = 0; ti < 4; ++ti) {
                f32x4 xv = *(const f32x4*)&Xc[tg + 32 * ti][dq * 4];
                acc[ti][0] += dot4(xv, w0);
                acc[ti][1] += dot4(xv, w1);
                acc[ti][2] += dot4(xv, w2);
            }
        }
    }
    // ypart[ds][tile64][t128][24]
    #pragma unroll
    for (int ti = 0; ti < 4; ++ti) {
        float* dst = ypart +
                     (((size_t)blockIdx.y * 64 + blockIdx.x) * 128 + (tg + 32 * ti)) * 24 +
                     og * 3;
        dst[0] = acc[ti][0];
        dst[1] = acc[ti][1];
        dst[2] = acc[ti][2];
    }
}

// ---------------- Kernel 2b: finalize — reduce partials, softmax, expert-core mix -------
__global__ __launch_bounds__(128) void finalize_mixed_kernel(const float* __restrict__ ypart,
                                                             const float* __restrict__ cores,
                                                             float* __restrict__ mixbuf) {
    __shared__ __align__(16) float Cs[2048];
    const int tid = threadIdx.x;
    #pragma unroll
    for (int i = 0; i < 4; ++i) {
        int idx = i * 128 + tid;
        ((f32x4*)Cs)[idx] = ((const f32x4*)cores)[idx];
    }
    __syncthreads();

    const int tok = blockIdx.x * 128 + tid;
    const int tile = tok >> 7, t = tok & 127;  // 128-token tiles

    float y[24];
    #pragma unroll
    for (int j = 0; j < 24; ++j) y[j] = 0.f;
    for (int ds = 0; ds < 8; ++ds) {
        const float* src = ypart + (((size_t)ds * 64 + tile) * 128 + t) * 24;
        #pragma unroll
        for (int j = 0; j < 24; ++j) y[j] += src[j];
    }

    float mx = y[16];
    #pragma unroll
    for (int e = 1; e < 8; ++e) mx = fmaxf(mx, y[16 + e]);
    float p[8], psum = 0.f;
    #pragma unroll
    for (int e = 0; e < 8; ++e) { p[e] = __expf(y[16 + e] - mx); psum += p[e]; }
    const float inv = 1.0f / psum;

    float outq[16];
    #pragma unroll
    for (int q = 0; q < 16; ++q) outq[q] = 0.f;
    for (int e = 0; e < 8; ++e) {
        const float pe = p[e] * inv;
        #pragma unroll
        for (int r = 0; r < 16; ++r) {
            const float ar = y[r] * pe;
            #pragma unroll
            for (int q = 0; q < 16; ++q)
                outq[q] = fmaf(ar, Cs[(e * 16 + r) * 16 + q], outq[q]);
        }
    }
    #pragma unroll
    for (int q = 0; q < 4; ++q) {
        f32x4 v = {outq[q * 4 + 0], outq[q * 4 + 1], outq[q * 4 + 2], outq[q * 4 + 3]};
        *(f32x4*)&mixbuf[(size_t)tok * 16 + q * 4] = v;
    }
}

// ---------------- Kernel 3: 256x256-tile deep-pipelined GEMM + fused epilogue -----------
// EXACT round-6 structure (passing, 256.5 us, MfmaUtil 48.3%, conflicts 0).
// The explicit lgkmcnt(0) after barriers 1/3 is LOAD-BEARING FOR CORRECTNESS (rule #18):
// MFMAs are register-only and not pinned by asm "memory" clobbers or raw s_barrier, so
// without the forced drain the compiler can sink MFMA clusters (and their lgkmcnt waits)
// past the next barrier -> a wave crosses the barrier with ds_reads still pending while
// the next iteration's global_load_lds overwrites the same ring buffer (round-7 race).
__global__ __launch_bounds__(512, 2) void gemm_kernel(const unsigned short* __restrict__ xbf,
                                                      const unsigned short* __restrict__ wbf,
                                                      const float* __restrict__ bias,
                                                      const float* __restrict__ Bw,
                                                      const float* __restrict__ mixbuf,
                                                      float* __restrict__ out) {
    __shared__ __align__(16) unsigned short lds[4][2][256 * 32];  // 128 KiB

    const int bid = blockIdx.x;
    const int xcd = bid & 7;
    const int lid = bid >> 3;                 // 0..63
    const int tm = (lid >> 4) * 8 + xcd;      // 0..31
    const int tn = lid & 15;                  // 0..15
    const int m0 = tm * 256, n0 = tn * 256;

    const int tid = threadIdx.x;
    const int wave = tid >> 6, lane = tid & 63;
    const int wr = wave >> 2, wcn = wave & 3;  // 2x4 wave grid

    int aoff[2], boff[2];
    #pragma unroll
    for (int u = 0; u < 2; ++u) {
        int c = u * 512 + tid;
        int g = swz(c * 16);
        int grow = g >> 6, gc8 = (g >> 4) & 3;
        aoff[u] = (m0 + grow) * D_DIM + gc8 * 8;
        boff[u] = (n0 + grow) * D_DIM + gc8 * 8;
    }

    const int tA = lane & 15, kq = lane >> 4;
    int aRd[8], bRd[4];
    #pragma unroll
    for (int mi = 0; mi < 8; ++mi)
        aRd[mi] = swz((wr * 128 + mi * 16 + tA) * 64 + kq * 16);
    #pragma unroll
    for (int ni = 0; ni < 4; ++ni)
        bRd[ni] = swz((wcn * 64 + ni * 16 + tA) * 64 + kq * 16);

    f32x4 acc[8][4];
    const f32x4 fz = {0.f, 0.f, 0.f, 0.f};
    #pragma unroll
    for (int mi = 0; mi < 8; ++mi)
        #pragma unroll
        for (int ni = 0; ni < 4; ++ni) acc[mi][ni] = fz;

#define STAGE_UNIT(sb, kt, u, isA)                                                        \
    do {                                                                                  \
        const unsigned short* gsrc =                                                      \
            (isA) ? (xbf + aoff[u] + (kt)*BK) : (wbf + boff[u] + (kt)*BK);                \
        __builtin_amdgcn_global_load_lds(                                                 \
            (const __attribute__((address_space(1))) void*)gsrc,                          \
            (__attribute__((address_space(3))) void*)(&lds[sb][(isA) ? 0 : 1]             \
                                                         [((u)*512 + wave * 64) * 8]),    \
            16, 0, 0);                                                                    \
    } while (0)

// One K-tile iteration (2 phases, 4 barriers). STG: 0/1 literal (stage K-tile KT into
// SBUF). VMC: literal vmcnt count for the phase-1 counted wait.
#define K_ITER(BUF, SBUF, KT, STG, VMC)                                                   \
    {                                                                                     \
        const char* Ab = (const char*)&lds[BUF][0][0];                                    \
        const char* Bb = (const char*)&lds[BUF][1][0];                                    \
        bf16x8 b0 = __builtin_bit_cast(bf16x8, *(const u16x8*)(Bb + bRd[0]));             \
        bf16x8 b1 = __builtin_bit_cast(bf16x8, *(const u16x8*)(Bb + bRd[1]));             \
        bf16x8 b2 = __builtin_bit_cast(bf16x8, *(const u16x8*)(Bb + bRd[2]));             \
        bf16x8 b3 = __builtin_bit_cast(bf16x8, *(const u16x8*)(Bb + bRd[3]));             \
        bf16x8 a0 = __builtin_bit_cast(bf16x8, *(const u16x8*)(Ab + aRd[0]));             \
        bf16x8 a1 = __builtin_bit_cast(bf16x8, *(const u16x8*)(Ab + aRd[1]));             \
        bf16x8 a2 = __builtin_bit_cast(bf16x8, *(const u16x8*)(Ab + aRd[2]));             \
        bf16x8 a3 = __builtin_bit_cast(bf16x8, *(const u16x8*)(Ab + aRd[3]));             \
        if (STG) {                                                                        \
            STAGE_UNIT(SBUF, KT, 0, 1);                                                   \
            STAGE_UNIT(SBUF, KT, 1, 1);                                                   \
        }                                                                                 \
        asm volatile("" ::: "memory");                                                    \
        __builtin_amdgcn_s_barrier();                                                     \
        asm volatile("s_waitcnt lgkmcnt(0)" ::: "memory");                                \
        __builtin_amdgcn_s_setprio(1);                                                    \
        acc[0][0] = __builtin_amdgcn_mfma_f32_16x16x32_bf16(a0, b0, acc[0][0], 0, 0, 0);  \
        acc[0][1] = __builtin_amdgcn_mfma_f32_16x16x32_bf16(a0, b1, acc[0][1], 0, 0, 0);  \
        acc[0][2] = __builtin_amdgcn_mfma_f32_16x16x32_bf16(a0, b2, acc[0][2], 0, 0, 0);  \
        acc[0][3] = __builtin_amdgcn_mfma_f32_16x16x32_bf16(a0, b3, acc[0][3], 0, 0, 0);  \
        acc[1][0] = __builtin_amdgcn_mfma_f32_16x16x32_bf16(a1, b0, acc[1][0], 0, 0, 0);  \
        acc[1][1] = __builtin_amdgcn_mfma_f32_16x16x32_bf16(a1, b1, acc[1][1], 0, 0, 0);  \
        acc[1][2] = __builtin_amdgcn_mfma_f32_16x16x32_bf16(a1, b2, acc[1][2], 0, 0, 0);  \
        acc[1][3] = __builtin_amdgcn_mfma_f32_16x16x32_bf16(a1, b3, acc[1][3], 0, 0, 0);  \
        acc[2][0] = __builtin_amdgcn_mfma_f32_16x16x32_bf16(a2, b0, acc[2][0], 0, 0, 0);  \
        acc[2][1] = __builtin_amdgcn_mfma_f32_16x16x32_bf16(a2, b1, acc[2][1], 0, 0, 0);  \
        acc[2][2] = __builtin_amdgcn_mfma_f32_16x16x32_bf16(a2, b2, acc[2][2], 0, 0, 0);  \
        acc[2][3] = __builtin_amdgcn_mfma_f32_16x16x32_bf16(a2, b3, acc[2][3], 0, 0, 0);  \
        acc[3][0] = __builtin_amdgcn_mfma_f32_16x16x32_bf16(a3, b0, acc[3][0], 0, 0, 0);  \
        acc[3][1] = __builtin_amdgcn_mfma_f32_16x16x32_bf16(a3, b1, acc[3][1], 0, 0, 0);  \
        acc[3][2] = __builtin_amdgcn_mfma_f32_16x16x32_bf16(a3, b2, acc[3][2], 0, 0, 0);  \
        acc[3][3] = __builtin_amdgcn_mfma_f32_16x16x32_bf16(a3, b3, acc[3][3], 0, 0, 0);  \
        __builtin_amdgcn_s_setprio(0);                                                    \
        asm volatile("" ::: "memory");                                                    \
        __builtin_amdgcn_s_barrier();                                                     \
        asm volatile("" ::: "memory");                                                    \
        bf16x8 a4 = __builtin_bit_cast(bf16x8, *(const u16x8*)(Ab + aRd[4]));             \
        bf16x8 a5 = __builtin_bit_cast(bf16x8, *(const u16x8*)(Ab + aRd[5]));             \
        bf16x8 a6 = __builtin_bit_cast(bf16x8, *(const u16x8*)(Ab + aRd[6]));             \
        bf16x8 a7 = __builtin_bit_cast(bf16x8, *(const u16x8*)(Ab + aRd[7]));             \
        if (STG) {                                                                        \
            STAGE_UNIT(SBUF, KT, 0, 0);                                                   \
            STAGE_UNIT(SBUF, KT, 1, 0);                                                   \
        }                                                                                 \
        asm volatile("s_waitcnt vmcnt(" #VMC ")" ::: "memory");                           \
        __builtin_amdgcn_s_barrier();                                                     \
        asm volatile("s_waitcnt lgkmcnt(0)" ::: "memory");                                \
        __builtin_amdgcn_s_setprio(1);                                                    \
        acc[4][0] = __builtin_amdgcn_mfma_f32_16x16x32_bf16(a4, b0, acc[4][0], 0, 0, 0);  \
        acc[4][1] = __builtin_amdgcn_mfma_f32_16x16x32_bf16(a4, b1, acc[4][1], 0, 0, 0);  \
        acc[4][2] = __builtin_amdgcn_mfma_f32_16x16x32_bf16(a4, b2, acc[4][2], 0, 0, 0);  \
        acc[4][3] = __builtin_amdgcn_mfma_f32_16x16x32_bf16(a4, b3, acc[4][3], 0, 0, 0);  \
        acc[5][0] = __builtin_amdgcn_mfma_f32_16x16x32_bf16(a5, b0, acc[5][0], 0, 0, 0);  \
        acc[5][1] = __builtin_amdgcn_mfma_f32_16x16x32_bf16(a5, b1, acc[5][1], 0, 0, 0);  \
        acc[5][2] = __builtin_amdgcn_mfma_f32_16x16x32_bf16(a5, b2, acc[5][2], 0, 0, 0);  \
        acc[5][3] = __builtin_amdgcn_mfma_f32_16x16x32_bf16(a5, b3, acc[5][3], 0, 0, 0);  \
        acc[6][0] = __builtin_amdgcn_mfma_f32_16x16x32_bf16(a6, b0, acc[6][0], 0, 0, 0);  \
        acc[6][1] = __builtin_amdgcn_mfma_f32_16x16x32_bf16(a6, b1, acc[6][1], 0, 0, 0);  \
        acc[6][2] = __builtin_amdgcn_mfma_f32_16x16x32_bf16(a6, b2, acc[6][2], 0, 0, 0);  \
        acc[6][3] = __builtin_amdgcn_mfma_f32_16x16x32_bf16(a6, b3, acc[6][3], 0, 0, 0);  \
        acc[7][0] = __builtin_amdgcn_mfma_f32_16x16x32_bf16(a7, b0, acc[7][0], 0, 0, 0);  \
        acc[7][1] = __builtin_amdgcn_mfma_f32_16x16x32_bf16(a7, b1, acc[7][1], 0, 0, 0);  \
        acc[7][2] = __builtin_amdgcn_mfma_f32_16x16x32_bf16(a7, b2, acc[7][2], 0, 0, 0);  \
        acc[7][3] = __builtin_amdgcn_mfma_f32_16x16x32_bf16(a7, b3, acc[7][3], 0, 0, 0);  \
        __builtin_amdgcn_s_setprio(0);                                                    \
        asm volatile("" ::: "memory");                                                    \
        __builtin_amdgcn_s_barrier();                                                     \
        asm volatile("" ::: "memory");                                                    \
    }

    // ---- prologue: stage K-tiles 0..2 (12 gload_lds/thread), wait all but K1,K2 ----
    #pragma unroll
    for (int kt = 0; kt < 3; ++kt) {
        STAGE_UNIT(kt, kt, 0, 1);
        STAGE_UNIT(kt, kt, 1, 1);
        STAGE_UNIT(kt, kt, 0, 0);
        STAGE_UNIT(kt, kt, 1, 0);
    }
    asm volatile("s_waitcnt vmcnt(8)" ::: "memory");
    __builtin_amdgcn_s_barrier();
    asm volatile("" ::: "memory");

    // ---- main loop: K-tiles 0..123 (staging always active, steady-state vmcnt(8)) ----
    for (int jj = 0; jj < 31; ++jj) {
        #pragma unroll
        for (int i = 0; i < 4; ++i) {
            const int j = jj * 4 + i;
            const int kt = j + 3;  // 3..126 < NKT: always stage
            K_ITER(i, (i + 3) & 3, kt, 1, 8);
        }
    }
    // ---- peeled tail: K-tiles 124..127 with explicit drains (race fix, round 6) ----
    K_ITER(0, 3, 127, 1, 8);  // j=124: stage kt=127; steady-state wait (kt=125 landed)
    K_ITER(1, 0, 0, 0, 4);    // j=125: no stage; drain to 4 -> kt=126 landed
    K_ITER(2, 0, 0, 0, 0);    // j=126: no stage; drain all -> kt=127 landed
    K_ITER(3, 0, 0, 0, 0);    // j=127: no stage; vmcnt(0) is a no-op
#undef K_ITER
#undef STAGE_UNIT

    // ---- epilogue: C/D layout col=lane&15, row=(lane>>4)*4+j ----
    const int colq = lane & 15, rq = lane >> 4;
    f32x4 bwv[4][4];
    float bcol[4];
    #pragma unroll
    for (int ni = 0; ni < 4; ++ni) {
        const int col = n0 + wcn * 64 + ni * 16 + colq;
        bcol[ni] = bias[col];
        #pragma unroll
        for (int k = 0; k < 4; ++k) bwv[ni][k] = *(const f32x4*)&Bw[(size_t)col * 16 + k * 4];
    }
    #pragma unroll
    for (int mi = 0; mi < 8; ++mi) {
        #pragma unroll
        for (int j = 0; j < 4; ++j) {
            const int row = m0 + wr * 128 + mi * 16 + rq * 4 + j;
            const f32x4* mx = (const f32x4*)&mixbuf[(size_t)row * 16];
            const f32x4 m0v = mx[0], m1v = mx[1], m2v = mx[2], m3v = mx[3];
            #pragma unroll
            for (int ni = 0; ni < 4; ++ni) {
                const int col = n0 + wcn * 64 + ni * 16 + colq;
                const float lora = dot4(m0v, bwv[ni][0]) + dot4(m1v, bwv[ni][1]) +
                                   dot4(m2v, bwv[ni][2]) + dot4(m3v, bwv[ni][3]);
                out[(size_t)row * O_DIM + col] = acc[mi][ni][j] + bcol[ni] + SCALE_F * lora;
            }
        }
    }
}

extern "C" void kernel_launch(void* const* d_in, const int* in_sizes, int n_in,
                              void* d_out, int out_size, void* d_ws, size_t ws_size,
                              hipStream_t stream) {
    const float* x        = (const float*)d_in[0];
    const float* W_base   = (const float*)d_in[1];
    const float* b_base   = (const float*)d_in[2];
    const float* A_w      = (const float*)d_in[3];
    const float* B_w      = (const float*)d_in[4];
    const float* router_w = (const float*)d_in[5];
    const float* cores    = (const float*)d_in[6];
    float* out = (float*)d_out;

    char* ws = (char*)d_ws;
    unsigned short* xbf = (unsigned short*)ws;                                   // 64 MiB
    unsigned short* wbf = (unsigned short*)(ws + (size_t)M_DIM * D_DIM * 2);     // 32 MiB
    char* after_w = ws + (size_t)M_DIM * D_DIM * 2 + (size_t)O_DIM * D_DIM * 2;
    float* mixbuf = (float*)after_w;                                             // 512 KiB
    float* ypart  = (float*)(after_w + (size_t)M_DIM * 16 * 4);                  // 6 MiB

    convert_bf16_kernel<<<2048, 256, 0, stream>>>(W_base, wbf, (O_DIM * D_DIM) / 4);
    partial_mixed_kernel<<<dim3(64, 8), 256, 0, stream>>>(x, A_w, router_w, xbf, ypart);
    finalize_mixed_kernel<<<64, 128, 0, stream>>>(ypart, cores, mixbuf);
    gemm_kernel<<<512, 512, 0, stream>>>(xbf, wbf, b_base, B_w, mixbuf, out);
}

// Round 9
// 337.792 us; speedup vs baseline: 1.1657x; 1.1657x over previous
//
#include <hip/hip_runtime.h>
#include <stdint.h>

#define D_DIM 4096
#define O_DIM 4096
#define M_DIM 8192
#define SCALE_F 2.0f
#define BK 32
#define NKT 128  // D_DIM / BK

typedef __attribute__((ext_vector_type(4))) float f32x4;
typedef __attribute__((ext_vector_type(8))) __bf16 bf16x8;
typedef __attribute__((ext_vector_type(8))) unsigned short u16x8;

__device__ __forceinline__ unsigned short f32_to_bf16_bits(float f) {
    union { float f; uint32_t u; } v; v.f = f;
    return (unsigned short)((v.u + 0x7FFFu + ((v.u >> 16) & 1u)) >> 16);
}

__device__ __forceinline__ float dot4(f32x4 a, f32x4 b) {
    return fmaf(a.x, b.x, fmaf(a.y, b.y, fmaf(a.z, b.z, a.w * b.w)));
}

// swizzle involution on byte offsets within a 16 KiB [256 rows][64 B] tile:
// XOR bits 4-6 with bits 7-9. Verified: SQ_LDS_BANK_CONFLICT == 0 (rounds 3-8).
__device__ __forceinline__ int swz(int b) { return b ^ (((b >> 7) & 7) << 4); }

// ---------------- Kernel 1: f32 -> bf16 convert (W_base) ----------------
__global__ __launch_bounds__(256) void convert_bf16_kernel(const float* __restrict__ src,
                                                           unsigned short* __restrict__ dst,
                                                           int n4) {
    int stride = gridDim.x * blockDim.x;
    for (int i = blockIdx.x * blockDim.x + threadIdx.x; i < n4; i += stride) {
        f32x4 v = ((const f32x4*)src)[i];
        ushort4 o;
        o.x = f32_to_bf16_bits(v.x);
        o.y = f32_to_bf16_bits(v.y);
        o.z = f32_to_bf16_bits(v.z);
        o.w = f32_to_bf16_bits(v.w);
        ((ushort4*)dst)[i] = o;
    }
}

// ---------------- Kernel 2a: partial Y + fused x->bf16 convert (round-3 version) --------
// grid (256 token-tiles of 32, 8 D-splits), 256 threads, 29 KiB LDS (5 blocks/CU).
// Round-7/8's 128-token variant (80 KiB LDS) regressed ~+55 us: occupancy loss starved
// the HBM staging. Keep the high-occupancy version.
__global__ __launch_bounds__(256) void partial_mixed_kernel(const float* __restrict__ x,
                                                            const float* __restrict__ A_w,
                                                            const float* __restrict__ router_w,
                                                            unsigned short* __restrict__ xbf,
                                                            float* __restrict__ ypart) {
    __shared__ __align__(16) float Xc[32][132];
    __shared__ __align__(16) float Wc[24][132];

    const int tid = threadIdx.x;
    const int t0 = blockIdx.x * 32;
    const int d0 = blockIdx.y * 512;

    const int tg = tid >> 3;
    const int og = tid & 7;
    float acc0 = 0.f, acc1 = 0.f, acc2 = 0.f;

    for (int sub = 0; sub < 4; ++sub) {
        const int dbase = d0 + sub * 128;
        __syncthreads();
        #pragma unroll
        for (int i = 0; i < 4; ++i) {
            int idx = i * 256 + tid;
            int t = idx >> 5, dq = idx & 31;
            f32x4 v = *(const f32x4*)&x[(size_t)(t0 + t) * D_DIM + dbase + dq * 4];
            *(f32x4*)&Xc[t][dq * 4] = v;
            ushort4 o;
            o.x = f32_to_bf16_bits(v.x);
            o.y = f32_to_bf16_bits(v.y);
            o.z = f32_to_bf16_bits(v.z);
            o.w = f32_to_bf16_bits(v.w);
            *(ushort4*)&xbf[(size_t)(t0 + t) * D_DIM + dbase + dq * 4] = o;
        }
        #pragma unroll
        for (int i = 0; i < 3; ++i) {
            int idx = i * 256 + tid;
            int r = idx >> 5, dq = idx & 31;
            const float* src = (r < 16) ? (A_w + (size_t)r * D_DIM)
                                        : (router_w + (size_t)(r - 16) * D_DIM);
            *(f32x4*)&Wc[r][dq * 4] = *(const f32x4*)&src[dbase + dq * 4];
        }
        __syncthreads();
        #pragma unroll
        for (int dq = 0; dq < 32; ++dq) {
            f32x4 xv = *(const f32x4*)&Xc[tg][dq * 4];
            acc0 += dot4(xv, *(const f32x4*)&Wc[og * 3 + 0][dq * 4]);
            acc1 += dot4(xv, *(const f32x4*)&Wc[og * 3 + 1][dq * 4]);
            acc2 += dot4(xv, *(const f32x4*)&Wc[og * 3 + 2][dq * 4]);
        }
    }
    float* dst = ypart + (((size_t)blockIdx.y * 256 + blockIdx.x) * 32 + tg) * 24 + og * 3;
    dst[0] = acc0; dst[1] = acc1; dst[2] = acc2;
}

// ---------------- Kernel 2b: finalize — reduce partials, softmax, expert-core mix -------
__global__ __launch_bounds__(128) void finalize_mixed_kernel(const float* __restrict__ ypart,
                                                             const float* __restrict__ cores,
                                                             float* __restrict__ mixbuf) {
    __shared__ __align__(16) float Cs[2048];
    const int tid = threadIdx.x;
    #pragma unroll
    for (int i = 0; i < 4; ++i) {
        int idx = i * 128 + tid;
        ((f32x4*)Cs)[idx] = ((const f32x4*)cores)[idx];
    }
    __syncthreads();

    const int tok = blockIdx.x * 128 + tid;
    const int tile = tok >> 5, t = tok & 31;  // 32-token tiles (round-3 layout)

    float y[24];
    #pragma unroll
    for (int j = 0; j < 24; ++j) y[j] = 0.f;
    for (int ds = 0; ds < 8; ++ds) {
        const float* src = ypart + (((size_t)ds * 256 + tile) * 32 + t) * 24;
        #pragma unroll
        for (int j = 0; j < 24; ++j) y[j] += src[j];
    }

    float mx = y[16];
    #pragma unroll
    for (int e = 1; e < 8; ++e) mx = fmaxf(mx, y[16 + e]);
    float p[8], psum = 0.f;
    #pragma unroll
    for (int e = 0; e < 8; ++e) { p[e] = __expf(y[16 + e] - mx); psum += p[e]; }
    const float inv = 1.0f / psum;

    float outq[16];
    #pragma unroll
    for (int q = 0; q < 16; ++q) outq[q] = 0.f;
    for (int e = 0; e < 8; ++e) {
        const float pe = p[e] * inv;
        #pragma unroll
        for (int r = 0; r < 16; ++r) {
            const float ar = y[r] * pe;
            #pragma unroll
            for (int q = 0; q < 16; ++q)
                outq[q] = fmaf(ar, Cs[(e * 16 + r) * 16 + q], outq[q]);
        }
    }
    #pragma unroll
    for (int q = 0; q < 4; ++q) {
        f32x4 v = {outq[q * 4 + 0], outq[q * 4 + 1], outq[q * 4 + 2], outq[q * 4 + 3]};
        *(f32x4*)&mixbuf[(size_t)tok * 16 + q * 4] = v;
    }
}

// ---------------- Kernel 3: 256x256-tile deep-pipelined GEMM + fused epilogue -----------
// Round-8 structure with RELAXED lgkmcnt placement: the full drain after each opening
// barrier is gone; the compiler's dependency-tracked lgkmcnt ladder covers MFMA inputs
// (typed ds_reads, not inline asm -> rule #18 hazard doesn't apply). Correctness needs
// only ONE lgkmcnt(0) before the phase-1 CLOSING barrier: all of iter j's ds_reads of
// buf j drain before iter j+1's staging (issued after that barrier) can overwrite it.
// vmcnt accounting and race-fixed tail peel unchanged from round 6.
__global__ __launch_bounds__(512, 2) void gemm_kernel(const unsigned short* __restrict__ xbf,
                                                      const unsigned short* __restrict__ wbf,
                                                      const float* __restrict__ bias,
                                                      const float* __restrict__ Bw,
                                                      const float* __restrict__ mixbuf,
                                                      float* __restrict__ out) {
    __shared__ __align__(16) unsigned short lds[4][2][256 * 32];  // 128 KiB

    const int bid = blockIdx.x;
    const int xcd = bid & 7;
    const int lid = bid >> 3;                 // 0..63
    const int tm = (lid >> 4) * 8 + xcd;      // 0..31
    const int tn = lid & 15;                  // 0..15
    const int m0 = tm * 256, n0 = tn * 256;

    const int tid = threadIdx.x;
    const int wave = tid >> 6, lane = tid & 63;
    const int wr = wave >> 2, wcn = wave & 3;  // 2x4 wave grid

    int aoff[2], boff[2];
    #pragma unroll
    for (int u = 0; u < 2; ++u) {
        int c = u * 512 + tid;
        int g = swz(c * 16);
        int grow = g >> 6, gc8 = (g >> 4) & 3;
        aoff[u] = (m0 + grow) * D_DIM + gc8 * 8;
        boff[u] = (n0 + grow) * D_DIM + gc8 * 8;
    }

    const int tA = lane & 15, kq = lane >> 4;
    int aRd[8], bRd[4];
    #pragma unroll
    for (int mi = 0; mi < 8; ++mi)
        aRd[mi] = swz((wr * 128 + mi * 16 + tA) * 64 + kq * 16);
    #pragma unroll
    for (int ni = 0; ni < 4; ++ni)
        bRd[ni] = swz((wcn * 64 + ni * 16 + tA) * 64 + kq * 16);

    f32x4 acc[8][4];
    const f32x4 fz = {0.f, 0.f, 0.f, 0.f};
    #pragma unroll
    for (int mi = 0; mi < 8; ++mi)
        #pragma unroll
        for (int ni = 0; ni < 4; ++ni) acc[mi][ni] = fz;

#define STAGE_UNIT(sb, kt, u, isA)                                                        \
    do {                                                                                  \
        const unsigned short* gsrc =                                                      \
            (isA) ? (xbf + aoff[u] + (kt)*BK) : (wbf + boff[u] + (kt)*BK);                \
        __builtin_amdgcn_global_load_lds(                                                 \
            (const __attribute__((address_space(1))) void*)gsrc,                          \
            (__attribute__((address_space(3))) void*)(&lds[sb][(isA) ? 0 : 1]             \
                                                         [((u)*512 + wave * 64) * 8]),    \
            16, 0, 0);                                                                    \
    } while (0)

// One K-tile iteration (2 phases, 4 barriers). STG: 0/1 literal (stage K-tile KT into
// SBUF). VMC: literal vmcnt count for the phase-1 counted wait.
#define K_ITER(BUF, SBUF, KT, STG, VMC)                                                   \
    {                                                                                     \
        const char* Ab = (const char*)&lds[BUF][0][0];                                    \
        const char* Bb = (const char*)&lds[BUF][1][0];                                    \
        bf16x8 b0 = __builtin_bit_cast(bf16x8, *(const u16x8*)(Bb + bRd[0]));             \
        bf16x8 b1 = __builtin_bit_cast(bf16x8, *(const u16x8*)(Bb + bRd[1]));             \
        bf16x8 b2 = __builtin_bit_cast(bf16x8, *(const u16x8*)(Bb + bRd[2]));             \
        bf16x8 b3 = __builtin_bit_cast(bf16x8, *(const u16x8*)(Bb + bRd[3]));             \
        bf16x8 a0 = __builtin_bit_cast(bf16x8, *(const u16x8*)(Ab + aRd[0]));             \
        bf16x8 a1 = __builtin_bit_cast(bf16x8, *(const u16x8*)(Ab + aRd[1]));             \
        bf16x8 a2 = __builtin_bit_cast(bf16x8, *(const u16x8*)(Ab + aRd[2]));             \
        bf16x8 a3 = __builtin_bit_cast(bf16x8, *(const u16x8*)(Ab + aRd[3]));             \
        if (STG) {                                                                        \
            STAGE_UNIT(SBUF, KT, 0, 1);                                                   \
            STAGE_UNIT(SBUF, KT, 1, 1);                                                   \
        }                                                                                 \
        asm volatile("" ::: "memory");                                                    \
        __builtin_amdgcn_s_barrier();                                                     \
        asm volatile("" ::: "memory");                                                    \
        __builtin_amdgcn_s_setprio(1);                                                    \
        acc[0][0] = __builtin_amdgcn_mfma_f32_16x16x32_bf16(a0, b0, acc[0][0], 0, 0, 0);  \
        acc[0][1] = __builtin_amdgcn_mfma_f32_16x16x32_bf16(a0, b1, acc[0][1], 0, 0, 0);  \
        acc[0][2] = __builtin_amdgcn_mfma_f32_16x16x32_bf16(a0, b2, acc[0][2], 0, 0, 0);  \
        acc[0][3] = __builtin_amdgcn_mfma_f32_16x16x32_bf16(a0, b3, acc[0][3], 0, 0, 0);  \
        acc[1][0] = __builtin_amdgcn_mfma_f32_16x16x32_bf16(a1, b0, acc[1][0], 0, 0, 0);  \
        acc[1][1] = __builtin_amdgcn_mfma_f32_16x16x32_bf16(a1, b1, acc[1][1], 0, 0, 0);  \
        acc[1][2] = __builtin_amdgcn_mfma_f32_16x16x32_bf16(a1, b2, acc[1][2], 0, 0, 0);  \
        acc[1][3] = __builtin_amdgcn_mfma_f32_16x16x32_bf16(a1, b3, acc[1][3], 0, 0, 0);  \
        acc[2][0] = __builtin_amdgcn_mfma_f32_16x16x32_bf16(a2, b0, acc[2][0], 0, 0, 0);  \
        acc[2][1] = __builtin_amdgcn_mfma_f32_16x16x32_bf16(a2, b1, acc[2][1], 0, 0, 0);  \
        acc[2][2] = __builtin_amdgcn_mfma_f32_16x16x32_bf16(a2, b2, acc[2][2], 0, 0, 0);  \
        acc[2][3] = __builtin_amdgcn_mfma_f32_16x16x32_bf16(a2, b3, acc[2][3], 0, 0, 0);  \
        acc[3][0] = __builtin_amdgcn_mfma_f32_16x16x32_bf16(a3, b0, acc[3][0], 0, 0, 0);  \
        acc[3][1] = __builtin_amdgcn_mfma_f32_16x16x32_bf16(a3, b1, acc[3][1], 0, 0, 0);  \
        acc[3][2] = __builtin_amdgcn_mfma_f32_16x16x32_bf16(a3, b2, acc[3][2], 0, 0, 0);  \
        acc[3][3] = __builtin_amdgcn_mfma_f32_16x16x32_bf16(a3, b3, acc[3][3], 0, 0, 0);  \
        __builtin_amdgcn_s_setprio(0);                                                    \
        asm volatile("" ::: "memory");                                                    \
        __builtin_amdgcn_s_barrier();                                                     \
        asm volatile("" ::: "memory");                                                    \
        bf16x8 a4 = __builtin_bit_cast(bf16x8, *(const u16x8*)(Ab + aRd[4]));             \
        bf16x8 a5 = __builtin_bit_cast(bf16x8, *(const u16x8*)(Ab + aRd[5]));             \
        bf16x8 a6 = __builtin_bit_cast(bf16x8, *(const u16x8*)(Ab + aRd[6]));             \
        bf16x8 a7 = __builtin_bit_cast(bf16x8, *(const u16x8*)(Ab + aRd[7]));             \
        if (STG) {                                                                        \
            STAGE_UNIT(SBUF, KT, 0, 0);                                                   \
            STAGE_UNIT(SBUF, KT, 1, 0);                                                   \
        }                                                                                 \
        asm volatile("s_waitcnt vmcnt(" #VMC ")" ::: "memory");                           \
        __builtin_amdgcn_s_barrier();                                                     \
        asm volatile("" ::: "memory");                                                    \
        __builtin_amdgcn_s_setprio(1);                                                    \
        acc[4][0] = __builtin_amdgcn_mfma_f32_16x16x32_bf16(a4, b0, acc[4][0], 0, 0, 0);  \
        acc[4][1] = __builtin_amdgcn_mfma_f32_16x16x32_bf16(a4, b1, acc[4][1], 0, 0, 0);  \
        acc[4][2] = __builtin_amdgcn_mfma_f32_16x16x32_bf16(a4, b2, acc[4][2], 0, 0, 0);  \
        acc[4][3] = __builtin_amdgcn_mfma_f32_16x16x32_bf16(a4, b3, acc[4][3], 0, 0, 0);  \
        acc[5][0] = __builtin_amdgcn_mfma_f32_16x16x32_bf16(a5, b0, acc[5][0], 0, 0, 0);  \
        acc[5][1] = __builtin_amdgcn_mfma_f32_16x16x32_bf16(a5, b1, acc[5][1], 0, 0, 0);  \
        acc[5][2] = __builtin_amdgcn_mfma_f32_16x16x32_bf16(a5, b2, acc[5][2], 0, 0, 0);  \
        acc[5][3] = __builtin_amdgcn_mfma_f32_16x16x32_bf16(a5, b3, acc[5][3], 0, 0, 0);  \
        acc[6][0] = __builtin_amdgcn_mfma_f32_16x16x32_bf16(a6, b0, acc[6][0], 0, 0, 0);  \
        acc[6][1] = __builtin_amdgcn_mfma_f32_16x16x32_bf16(a6, b1, acc[6][1], 0, 0, 0);  \
        acc[6][2] = __builtin_amdgcn_mfma_f32_16x16x32_bf16(a6, b2, acc[6][2], 0, 0, 0);  \
        acc[6][3] = __builtin_amdgcn_mfma_f32_16x16x32_bf16(a6, b3, acc[6][3], 0, 0, 0);  \
        acc[7][0] = __builtin_amdgcn_mfma_f32_16x16x32_bf16(a7, b0, acc[7][0], 0, 0, 0);  \
        acc[7][1] = __builtin_amdgcn_mfma_f32_16x16x32_bf16(a7, b1, acc[7][1], 0, 0, 0);  \
        acc[7][2] = __builtin_amdgcn_mfma_f32_16x16x32_bf16(a7, b2, acc[7][2], 0, 0, 0);  \
        acc[7][3] = __builtin_amdgcn_mfma_f32_16x16x32_bf16(a7, b3, acc[7][3], 0, 0, 0);  \
        __builtin_amdgcn_s_setprio(0);                                                    \
        asm volatile("s_waitcnt lgkmcnt(0)" ::: "memory");                                \
        __builtin_amdgcn_s_barrier();                                                     \
        asm volatile("" ::: "memory");                                                    \
    }

    // ---- prologue: stage K-tiles 0..2 (12 gload_lds/thread), wait all but K1,K2 ----
    #pragma unroll
    for (int kt = 0; kt < 3; ++kt) {
        STAGE_UNIT(kt, kt, 0, 1);
        STAGE_UNIT(kt, kt, 1, 1);
        STAGE_UNIT(kt, kt, 0, 0);
        STAGE_UNIT(kt, kt, 1, 0);
    }
    asm volatile("s_waitcnt vmcnt(8)" ::: "memory");
    __builtin_amdgcn_s_barrier();
    asm volatile("" ::: "memory");

    // ---- main loop: K-tiles 0..123 (staging always active, steady-state vmcnt(8)) ----
    for (int jj = 0; jj < 31; ++jj) {
        #pragma unroll
        for (int i = 0; i < 4; ++i) {
            const int j = jj * 4 + i;
            const int kt = j + 3;  // 3..126 < NKT: always stage
            K_ITER(i, (i + 3) & 3, kt, 1, 8);
        }
    }
    // ---- peeled tail: K-tiles 124..127 with explicit drains (race fix, round 6) ----
    K_ITER(0, 3, 127, 1, 8);  // j=124: stage kt=127; steady-state wait (kt=125 landed)
    K_ITER(1, 0, 0, 0, 4);    // j=125: no stage; drain to 4 -> kt=126 landed
    K_ITER(2, 0, 0, 0, 0);    // j=126: no stage; drain all -> kt=127 landed
    K_ITER(3, 0, 0, 0, 0);    // j=127: no stage; vmcnt(0) is a no-op
#undef K_ITER
#undef STAGE_UNIT

    // ---- epilogue: C/D layout col=lane&15, row=(lane>>4)*4+j ----
    const int colq = lane & 15, rq = lane >> 4;
    f32x4 bwv[4][4];
    float bcol[4];
    #pragma unroll
    for (int ni = 0; ni < 4; ++ni) {
        const int col = n0 + wcn * 64 + ni * 16 + colq;
        bcol[ni] = bias[col];
        #pragma unroll
        for (int k = 0; k < 4; ++k) bwv[ni][k] = *(const f32x4*)&Bw[(size_t)col * 16 + k * 4];
    }
    #pragma unroll
    for (int mi = 0; mi < 8; ++mi) {
        #pragma unroll
        for (int j = 0; j < 4; ++j) {
            const int row = m0 + wr * 128 + mi * 16 + rq * 4 + j;
            const f32x4* mx = (const f32x4*)&mixbuf[(size_t)row * 16];
            const f32x4 m0v = mx[0], m1v = mx[1], m2v = mx[2], m3v = mx[3];
            #pragma unroll
            for (int ni = 0; ni < 4; ++ni) {
                const int col = n0 + wcn * 64 + ni * 16 + colq;
                const float lora = dot4(m0v, bwv[ni][0]) + dot4(m1v, bwv[ni][1]) +
                                   dot4(m2v, bwv[ni][2]) + dot4(m3v, bwv[ni][3]);
                out[(size_t)row * O_DIM + col] = acc[mi][ni][j] + bcol[ni] + SCALE_F * lora;
            }
        }
    }
}

extern "C" void kernel_launch(void* const* d_in, const int* in_sizes, int n_in,
                              void* d_out, int out_size, void* d_ws, size_t ws_size,
                              hipStream_t stream) {
    const float* x        = (const float*)d_in[0];
    const float* W_base   = (const float*)d_in[1];
    const float* b_base   = (const float*)d_in[2];
    const float* A_w      = (const float*)d_in[3];
    const float* B_w      = (const float*)d_in[4];
    const float* router_w = (const float*)d_in[5];
    const float* cores    = (const float*)d_in[6];
    float* out = (float*)d_out;

    char* ws = (char*)d_ws;
    unsigned short* xbf = (unsigned short*)ws;                                   // 64 MiB
    unsigned short* wbf = (unsigned short*)(ws + (size_t)M_DIM * D_DIM * 2);     // 32 MiB
    char* after_w = ws + (size_t)M_DIM * D_DIM * 2 + (size_t)O_DIM * D_DIM * 2;
    float* mixbuf = (float*)after_w;                                             // 512 KiB
    float* ypart  = (float*)(after_w + (size_t)M_DIM * 16 * 4);                  // 6 MiB

    convert_bf16_kernel<<<2048, 256, 0, stream>>>(W_base, wbf, (O_DIM * D_DIM) / 4);
    partial_mixed_kernel<<<dim3(256, 8), 256, 0, stream>>>(x, A_w, router_w, xbf, ypart);
    finalize_mixed_kernel<<<64, 128, 0, stream>>>(ypart, cores, mixbuf);
    gemm_kernel<<<512, 512, 0, stream>>>(xbf, wbf, b_base, B_w, mixbuf, out);
}

// Round 10
// 327.960 us; speedup vs baseline: 1.2007x; 1.0300x over previous
//
#include <hip/hip_runtime.h>
#include <stdint.h>

#define D_DIM 4096
#define O_DIM 4096
#define M_DIM 8192
#define BK 32
#define NKT 128  // D_DIM / BK

typedef __attribute__((ext_vector_type(4))) float f32x4;
typedef __attribute__((ext_vector_type(8))) __bf16 bf16x8;
typedef __attribute__((ext_vector_type(8))) unsigned short u16x8;

__device__ __forceinline__ unsigned short f32_to_bf16_bits(float f) {
    union { float f; uint32_t u; } v; v.f = f;
    return (unsigned short)((v.u + 0x7FFFu + ((v.u >> 16) & 1u)) >> 16);
}

__device__ __forceinline__ float dot4(f32x4 a, f32x4 b) {
    return fmaf(a.x, b.x, fmaf(a.y, b.y, fmaf(a.z, b.z, a.w * b.w)));
}

// swizzle involution on byte offsets within a 16 KiB [256 rows][64 B] tile:
// XOR bits 4-6 with bits 7-9. Verified: SQ_LDS_BANK_CONFLICT == 0 (rounds 3-9).
__device__ __forceinline__ int swz(int b) { return b ^ (((b >> 7) & 7) << 4); }

// ---------------- Kernel 1: f32 -> bf16 convert (W_base) ----------------
__global__ __launch_bounds__(256) void convert_bf16_kernel(const float* __restrict__ src,
                                                           unsigned short* __restrict__ dst,
                                                           int n4) {
    int stride = gridDim.x * blockDim.x;
    for (int i = blockIdx.x * blockDim.x + threadIdx.x; i < n4; i += stride) {
        f32x4 v = ((const f32x4*)src)[i];
        ushort4 o;
        o.x = f32_to_bf16_bits(v.x);
        o.y = f32_to_bf16_bits(v.y);
        o.z = f32_to_bf16_bits(v.z);
        o.w = f32_to_bf16_bits(v.w);
        ((ushort4*)dst)[i] = o;
    }
}

// ---------------- Kernel 1b: Bw[4096][16] f32 -> bwbf[4096][32] bf16 (cols 16-31 zero) --
// One thread per output column; 64B contiguous write per thread.
__global__ __launch_bounds__(256) void bwbf_kernel(const float* __restrict__ Bw,
                                                   unsigned short* __restrict__ bwbf) {
    const int o = blockIdx.x * 256 + threadIdx.x;  // 0..4095
    ushort4* dst = (ushort4*)&bwbf[(size_t)o * 32];
    #pragma unroll
    for (int g = 0; g < 4; ++g) {
        f32x4 v = *(const f32x4*)&Bw[(size_t)o * 16 + g * 4];
        ushort4 u;
        u.x = f32_to_bf16_bits(v.x);
        u.y = f32_to_bf16_bits(v.y);
        u.z = f32_to_bf16_bits(v.z);
        u.w = f32_to_bf16_bits(v.w);
        dst[g] = u;
    }
    const ushort4 z = {0, 0, 0, 0};
    #pragma unroll
    for (int g = 4; g < 8; ++g) dst[g] = z;
}

// ---------------- Kernel 2a: partial Y + fused x->bf16 convert (reg double-buffered) ----
// grid (256 token-tiles of 32, 8 D-splits), 256 threads, 29 KiB LDS (5 blocks/CU).
// Round-10: T14 async-stage — sub+1's global loads issue right after the LDS writes,
// so HBM latency hides under the compute phase (round-9 version exposed it: 60 us vs
// 32 us BW floor).
__global__ __launch_bounds__(256) void partial_mixed_kernel(const float* __restrict__ x,
                                                            const float* __restrict__ A_w,
                                                            const float* __restrict__ router_w,
                                                            unsigned short* __restrict__ xbf,
                                                            float* __restrict__ ypart) {
    __shared__ __align__(16) float Xc[32][132];
    __shared__ __align__(16) float Wc[24][132];

    const int tid = threadIdx.x;
    const int t0 = blockIdx.x * 32;
    const int d0 = blockIdx.y * 512;

    const int tg = tid >> 3;
    const int og = tid & 7;
    float acc0 = 0.f, acc1 = 0.f, acc2 = 0.f;

    // per-thread staging coordinates
    int xt[4], xdq[4];
    #pragma unroll
    for (int i = 0; i < 4; ++i) {
        int idx = i * 256 + tid;
        xt[i] = idx >> 5;
        xdq[i] = idx & 31;
    }
    int wrr[3], wdq[3];
    const float* wsrc[3];
    #pragma unroll
    for (int i = 0; i < 3; ++i) {
        int idx = i * 256 + tid;
        wrr[i] = idx >> 5;
        wdq[i] = idx & 31;
        wsrc[i] = (wrr[i] < 16) ? (A_w + (size_t)wrr[i] * D_DIM)
                                : (router_w + (size_t)(wrr[i] - 16) * D_DIM);
    }

    // prologue: load sub-0 into registers
    f32x4 xr[4], wreg[3];
    #pragma unroll
    for (int i = 0; i < 4; ++i)
        xr[i] = *(const f32x4*)&x[(size_t)(t0 + xt[i]) * D_DIM + d0 + xdq[i] * 4];
    #pragma unroll
    for (int i = 0; i < 3; ++i) wreg[i] = *(const f32x4*)&wsrc[i][d0 + wdq[i] * 4];

    for (int sub = 0; sub < 4; ++sub) {
        const int dbase = d0 + sub * 128;
        __syncthreads();  // previous compute done; LDS free
        // write regs -> LDS; fused xbf convert
        #pragma unroll
        for (int i = 0; i < 4; ++i) {
            *(f32x4*)&Xc[xt[i]][xdq[i] * 4] = xr[i];
            ushort4 o;
            o.x = f32_to_bf16_bits(xr[i].x);
            o.y = f32_to_bf16_bits(xr[i].y);
            o.z = f32_to_bf16_bits(xr[i].z);
            o.w = f32_to_bf16_bits(xr[i].w);
            *(ushort4*)&xbf[(size_t)(t0 + xt[i]) * D_DIM + dbase + xdq[i] * 4] = o;
        }
        #pragma unroll
        for (int i = 0; i < 3; ++i) *(f32x4*)&Wc[wrr[i]][wdq[i] * 4] = wreg[i];
        // issue next sub's loads; they land during compute below
        if (sub < 3) {
            const int nb = dbase + 128;
            #pragma unroll
            for (int i = 0; i < 4; ++i)
                xr[i] = *(const f32x4*)&x[(size_t)(t0 + xt[i]) * D_DIM + nb + xdq[i] * 4];
            #pragma unroll
            for (int i = 0; i < 3; ++i) wreg[i] = *(const f32x4*)&wsrc[i][nb + wdq[i] * 4];
        }
        __syncthreads();
        #pragma unroll
        for (int dq = 0; dq < 32; ++dq) {
            f32x4 xv = *(const f32x4*)&Xc[tg][dq * 4];
            acc0 += dot4(xv, *(const f32x4*)&Wc[og * 3 + 0][dq * 4]);
            acc1 += dot4(xv, *(const f32x4*)&Wc[og * 3 + 1][dq * 4]);
            acc2 += dot4(xv, *(const f32x4*)&Wc[og * 3 + 2][dq * 4]);
        }
    }
    float* dst = ypart + (((size_t)blockIdx.y * 256 + blockIdx.x) * 32 + tg) * 24 + og * 3;
    dst[0] = acc0; dst[1] = acc1; dst[2] = acc2;
}

// ---------------- Kernel 2b: finalize — reduce, softmax, core-mix -> mixbf (bf16) -------
// Writes mixbf[8192][32] bf16 = 2*mixed in cols 0-15, zeros in 16-31 (SCALE folded in).
// The gemm consumes it as an extra rank-16 MFMA K-tile (lora fold).
__global__ __launch_bounds__(128) void finalize_mixed_kernel(const float* __restrict__ ypart,
                                                             const float* __restrict__ cores,
                                                             unsigned short* __restrict__ mixbf) {
    __shared__ __align__(16) float Cs[2048];
    const int tid = threadIdx.x;
    #pragma unroll
    for (int i = 0; i < 4; ++i) {
        int idx = i * 128 + tid;
        ((f32x4*)Cs)[idx] = ((const f32x4*)cores)[idx];
    }
    __syncthreads();

    const int tok = blockIdx.x * 128 + tid;
    const int tile = tok >> 5, t = tok & 31;

    float y[24];
    #pragma unroll
    for (int j = 0; j < 24; ++j) y[j] = 0.f;
    for (int ds = 0; ds < 8; ++ds) {
        const float* src = ypart + (((size_t)ds * 256 + tile) * 32 + t) * 24;
        #pragma unroll
        for (int j = 0; j < 24; ++j) y[j] += src[j];
    }

    float mx = y[16];
    #pragma unroll
    for (int e = 1; e < 8; ++e) mx = fmaxf(mx, y[16 + e]);
    float p[8], psum = 0.f;
    #pragma unroll
    for (int e = 0; e < 8; ++e) { p[e] = __expf(y[16 + e] - mx); psum += p[e]; }
    const float inv = 1.0f / psum;

    float outq[16];
    #pragma unroll
    for (int q = 0; q < 16; ++q) outq[q] = 0.f;
    for (int e = 0; e < 8; ++e) {
        const float pe = p[e] * inv;
        #pragma unroll
        for (int r = 0; r < 16; ++r) {
            const float ar = y[r] * pe;
            #pragma unroll
            for (int q = 0; q < 16; ++q)
                outq[q] = fmaf(ar, Cs[(e * 16 + r) * 16 + q], outq[q]);
        }
    }
    ushort4* dst = (ushort4*)&mixbf[(size_t)tok * 32];
    #pragma unroll
    for (int g = 0; g < 4; ++g) {
        ushort4 u;
        u.x = f32_to_bf16_bits(2.0f * outq[g * 4 + 0]);
        u.y = f32_to_bf16_bits(2.0f * outq[g * 4 + 1]);
        u.z = f32_to_bf16_bits(2.0f * outq[g * 4 + 2]);
        u.w = f32_to_bf16_bits(2.0f * outq[g * 4 + 3]);
        dst[g] = u;
    }
    const ushort4 z = {0, 0, 0, 0};
    #pragma unroll
    for (int g = 4; g < 8; ++g) dst[g] = z;
}

// ---------------- Kernel 3: 256x256-tile deep-pipelined GEMM, lora folded into K-loop ---
// Round-9 structure (passing, 255 us) + round-10 change: the LoRA rank-16 update runs as
// ONE extra MFMA iteration. mixbf[256-token rows][32] and bwbf[256-col rows][32] have the
// exact [256][64B] tile shape of a K-tile, staged into buf 0 (free since iter 124) via a
// dedicated vmcnt(0)+barrier mini-prologue after the peeled tail — no vmcnt weaving.
// Epilogue is then acc + bias only (removes ~20 VALU + 2 loads per output).
__global__ __launch_bounds__(512, 2) void gemm_kernel(const unsigned short* __restrict__ xbf,
                                                      const unsigned short* __restrict__ wbf,
                                                      const float* __restrict__ bias,
                                                      const unsigned short* __restrict__ mixbf,
                                                      const unsigned short* __restrict__ bwbf,
                                                      float* __restrict__ out) {
    __shared__ __align__(16) unsigned short lds[4][2][256 * 32];  // 128 KiB

    const int bid = blockIdx.x;
    const int xcd = bid & 7;
    const int lid = bid >> 3;                 // 0..63
    const int tm = (lid >> 4) * 8 + xcd;      // 0..31
    const int tn = lid & 15;                  // 0..15
    const int m0 = tm * 256, n0 = tn * 256;

    const int tid = threadIdx.x;
    const int wave = tid >> 6, lane = tid & 63;
    const int wr = wave >> 2, wcn = wave & 3;  // 2x4 wave grid

    int aoff[2], boff[2], mmoff[2], mboff[2];
    #pragma unroll
    for (int u = 0; u < 2; ++u) {
        int c = u * 512 + tid;
        int g = swz(c * 16);
        int grow = g >> 6, gc8 = (g >> 4) & 3;
        aoff[u] = (m0 + grow) * D_DIM + gc8 * 8;
        boff[u] = (n0 + grow) * D_DIM + gc8 * 8;
        mmoff[u] = (m0 + grow) * 32 + gc8 * 8;
        mboff[u] = (n0 + grow) * 32 + gc8 * 8;
    }

    const int tA = lane & 15, kq = lane >> 4;
    int aRd[8], bRd[4];
    #pragma unroll
    for (int mi = 0; mi < 8; ++mi)
        aRd[mi] = swz((wr * 128 + mi * 16 + tA) * 64 + kq * 16);
    #pragma unroll
    for (int ni = 0; ni < 4; ++ni)
        bRd[ni] = swz((wcn * 64 + ni * 16 + tA) * 64 + kq * 16);

    f32x4 acc[8][4];
    const f32x4 fz = {0.f, 0.f, 0.f, 0.f};
    #pragma unroll
    for (int mi = 0; mi < 8; ++mi)
        #pragma unroll
        for (int ni = 0; ni < 4; ++ni) acc[mi][ni] = fz;

#define STAGE_UNIT(sb, kt, u, isA)                                                        \
    do {                                                                                  \
        const unsigned short* gsrc =                                                      \
            (isA) ? (xbf + aoff[u] + (kt)*BK) : (wbf + boff[u] + (kt)*BK);                \
        __builtin_amdgcn_global_load_lds(                                                 \
            (const __attribute__((address_space(1))) void*)gsrc,                          \
            (__attribute__((address_space(3))) void*)(&lds[sb][(isA) ? 0 : 1]             \
                                                         [((u)*512 + wave * 64) * 8]),    \
            16, 0, 0);                                                                    \
    } while (0)

#define STAGE_MIX(u, isA)                                                                 \
    do {                                                                                  \
        const unsigned short* gsrc = (isA) ? (mixbf + mmoff[u]) : (bwbf + mboff[u]);      \
        __builtin_amdgcn_global_load_lds(                                                 \
            (const __attribute__((address_space(1))) void*)gsrc,                          \
            (__attribute__((address_space(3))) void*)(&lds[0][(isA) ? 0 : 1]              \
                                                         [((u)*512 + wave * 64) * 8]),    \
            16, 0, 0);                                                                    \
    } while (0)

// One K-tile iteration (2 phases, 4 barriers). STG: 0/1 literal (stage K-tile KT into
// SBUF). VMC: literal vmcnt count for the phase-1 counted wait.
#define K_ITER(BUF, SBUF, KT, STG, VMC)                                                   \
    {                                                                                     \
        const char* Ab = (const char*)&lds[BUF][0][0];                                    \
        const char* Bb = (const char*)&lds[BUF][1][0];                                    \
        bf16x8 b0 = __builtin_bit_cast(bf16x8, *(const u16x8*)(Bb + bRd[0]));             \
        bf16x8 b1 = __builtin_bit_cast(bf16x8, *(const u16x8*)(Bb + bRd[1]));             \
        bf16x8 b2 = __builtin_bit_cast(bf16x8, *(const u16x8*)(Bb + bRd[2]));             \
        bf16x8 b3 = __builtin_bit_cast(bf16x8, *(const u16x8*)(Bb + bRd[3]));             \
        bf16x8 a0 = __builtin_bit_cast(bf16x8, *(const u16x8*)(Ab + aRd[0]));             \
        bf16x8 a1 = __builtin_bit_cast(bf16x8, *(const u16x8*)(Ab + aRd[1]));             \
        bf16x8 a2 = __builtin_bit_cast(bf16x8, *(const u16x8*)(Ab + aRd[2]));             \
        bf16x8 a3 = __builtin_bit_cast(bf16x8, *(const u16x8*)(Ab + aRd[3]));             \
        if (STG) {                                                                        \
            STAGE_UNIT(SBUF, KT, 0, 1);                                                   \
            STAGE_UNIT(SBUF, KT, 1, 1);                                                   \
        }                                                                                 \
        asm volatile("" ::: "memory");                                                    \
        __builtin_amdgcn_s_barrier();                                                     \
        asm volatile("" ::: "memory");                                                    \
        __builtin_amdgcn_s_setprio(1);                                                    \
        acc[0][0] = __builtin_amdgcn_mfma_f32_16x16x32_bf16(a0, b0, acc[0][0], 0, 0, 0);  \
        acc[0][1] = __builtin_amdgcn_mfma_f32_16x16x32_bf16(a0, b1, acc[0][1], 0, 0, 0);  \
        acc[0][2] = __builtin_amdgcn_mfma_f32_16x16x32_bf16(a0, b2, acc[0][2], 0, 0, 0);  \
        acc[0][3] = __builtin_amdgcn_mfma_f32_16x16x32_bf16(a0, b3, acc[0][3], 0, 0, 0);  \
        acc[1][0] = __builtin_amdgcn_mfma_f32_16x16x32_bf16(a1, b0, acc[1][0], 0, 0, 0);  \
        acc[1][1] = __builtin_amdgcn_mfma_f32_16x16x32_bf16(a1, b1, acc[1][1], 0, 0, 0);  \
        acc[1][2] = __builtin_amdgcn_mfma_f32_16x16x32_bf16(a1, b2, acc[1][2], 0, 0, 0);  \
        acc[1][3] = __builtin_amdgcn_mfma_f32_16x16x32_bf16(a1, b3, acc[1][3], 0, 0, 0);  \
        acc[2][0] = __builtin_amdgcn_mfma_f32_16x16x32_bf16(a2, b0, acc[2][0], 0, 0, 0);  \
        acc[2][1] = __builtin_amdgcn_mfma_f32_16x16x32_bf16(a2, b1, acc[2][1], 0, 0, 0);  \
        acc[2][2] = __builtin_amdgcn_mfma_f32_16x16x32_bf16(a2, b2, acc[2][2], 0, 0, 0);  \
        acc[2][3] = __builtin_amdgcn_mfma_f32_16x16x32_bf16(a2, b3, acc[2][3], 0, 0, 0);  \
        acc[3][0] = __builtin_amdgcn_mfma_f32_16x16x32_bf16(a3, b0, acc[3][0], 0, 0, 0);  \
        acc[3][1] = __builtin_amdgcn_mfma_f32_16x16x32_bf16(a3, b1, acc[3][1], 0, 0, 0);  \
        acc[3][2] = __builtin_amdgcn_mfma_f32_16x16x32_bf16(a3, b2, acc[3][2], 0, 0, 0);  \
        acc[3][3] = __builtin_amdgcn_mfma_f32_16x16x32_bf16(a3, b3, acc[3][3], 0, 0, 0);  \
        __builtin_amdgcn_s_setprio(0);                                                    \
        asm volatile("" ::: "memory");                                                    \
        __builtin_amdgcn_s_barrier();                                                     \
        asm volatile("" ::: "memory");                                                    \
        bf16x8 a4 = __builtin_bit_cast(bf16x8, *(const u16x8*)(Ab + aRd[4]));             \
        bf16x8 a5 = __builtin_bit_cast(bf16x8, *(const u16x8*)(Ab + aRd[5]));             \
        bf16x8 a6 = __builtin_bit_cast(bf16x8, *(const u16x8*)(Ab + aRd[6]));             \
        bf16x8 a7 = __builtin_bit_cast(bf16x8, *(const u16x8*)(Ab + aRd[7]));             \
        if (STG) {                                                                        \
            STAGE_UNIT(SBUF, KT, 0, 0);                                                   \
            STAGE_UNIT(SBUF, KT, 1, 0);                                                   \
        }                                                                                 \
        asm volatile("s_waitcnt vmcnt(" #VMC ")" ::: "memory");                           \
        __builtin_amdgcn_s_barrier();                                                     \
        asm volatile("" ::: "memory");                                                    \
        __builtin_amdgcn_s_setprio(1);                                                    \
        acc[4][0] = __builtin_amdgcn_mfma_f32_16x16x32_bf16(a4, b0, acc[4][0], 0, 0, 0);  \
        acc[4][1] = __builtin_amdgcn_mfma_f32_16x16x32_bf16(a4, b1, acc[4][1], 0, 0, 0);  \
        acc[4][2] = __builtin_amdgcn_mfma_f32_16x16x32_bf16(a4, b2, acc[4][2], 0, 0, 0);  \
        acc[4][3] = __builtin_amdgcn_mfma_f32_16x16x32_bf16(a4, b3, acc[4][3], 0, 0, 0);  \
        acc[5][0] = __builtin_amdgcn_mfma_f32_16x16x32_bf16(a5, b0, acc[5][0], 0, 0, 0);  \
        acc[5][1] = __builtin_amdgcn_mfma_f32_16x16x32_bf16(a5, b1, acc[5][1], 0, 0, 0);  \
        acc[5][2] = __builtin_amdgcn_mfma_f32_16x16x32_bf16(a5, b2, acc[5][2], 0, 0, 0);  \
        acc[5][3] = __builtin_amdgcn_mfma_f32_16x16x32_bf16(a5, b3, acc[5][3], 0, 0, 0);  \
        acc[6][0] = __builtin_amdgcn_mfma_f32_16x16x32_bf16(a6, b0, acc[6][0], 0, 0, 0);  \
        acc[6][1] = __builtin_amdgcn_mfma_f32_16x16x32_bf16(a6, b1, acc[6][1], 0, 0, 0);  \
        acc[6][2] = __builtin_amdgcn_mfma_f32_16x16x32_bf16(a6, b2, acc[6][2], 0, 0, 0);  \
        acc[6][3] = __builtin_amdgcn_mfma_f32_16x16x32_bf16(a6, b3, acc[6][3], 0, 0, 0);  \
        acc[7][0] = __builtin_amdgcn_mfma_f32_16x16x32_bf16(a7, b0, acc[7][0], 0, 0, 0);  \
        acc[7][1] = __builtin_amdgcn_mfma_f32_16x16x32_bf16(a7, b1, acc[7][1], 0, 0, 0);  \
        acc[7][2] = __builtin_amdgcn_mfma_f32_16x16x32_bf16(a7, b2, acc[7][2], 0, 0, 0);  \
        acc[7][3] = __builtin_amdgcn_mfma_f32_16x16x32_bf16(a7, b3, acc[7][3], 0, 0, 0);  \
        __builtin_amdgcn_s_setprio(0);                                                    \
        asm volatile("s_waitcnt lgkmcnt(0)" ::: "memory");                                \
        __builtin_amdgcn_s_barrier();                                                     \
        asm volatile("" ::: "memory");                                                    \
    }

    // ---- prologue: stage K-tiles 0..2 (12 gload_lds/thread), wait all but K1,K2 ----
    #pragma unroll
    for (int kt = 0; kt < 3; ++kt) {
        STAGE_UNIT(kt, kt, 0, 1);
        STAGE_UNIT(kt, kt, 1, 1);
        STAGE_UNIT(kt, kt, 0, 0);
        STAGE_UNIT(kt, kt, 1, 0);
    }
    asm volatile("s_waitcnt vmcnt(8)" ::: "memory");
    __builtin_amdgcn_s_barrier();
    asm volatile("" ::: "memory");

    // ---- main loop: K-tiles 0..123 (staging always active, steady-state vmcnt(8)) ----
    for (int jj = 0; jj < 31; ++jj) {
        #pragma unroll
        for (int i = 0; i < 4; ++i) {
            const int j = jj * 4 + i;
            const int kt = j + 3;  // 3..126 < NKT: always stage
            K_ITER(i, (i + 3) & 3, kt, 1, 8);
        }
    }
    // ---- peeled tail: K-tiles 124..127 with explicit drains (race fix, round 6) ----
    K_ITER(0, 3, 127, 1, 8);  // j=124: stage kt=127; steady-state wait (kt=125 landed)
    K_ITER(1, 0, 0, 0, 4);    // j=125: no stage; drain to 4 -> kt=126 landed
    K_ITER(2, 0, 0, 0, 0);    // j=126: no stage; drain all -> kt=127 landed
    K_ITER(3, 0, 0, 0, 0);    // j=127: no stage; vmcnt(0) is a no-op

    // ---- lora fold: stage mixbf/bwbf into buf 0 (free since iter 124), one extra iter --
    STAGE_MIX(0, 1);
    STAGE_MIX(1, 1);
    STAGE_MIX(0, 0);
    STAGE_MIX(1, 0);
    asm volatile("s_waitcnt vmcnt(0)" ::: "memory");
    __builtin_amdgcn_s_barrier();
    asm volatile("" ::: "memory");
    K_ITER(0, 0, 0, 0, 0);  // acc += (2*mixed) @ Bw^T  (K=32, cols 16-31 are zeros)
#undef K_ITER
#undef STAGE_MIX
#undef STAGE_UNIT

    // ---- epilogue: acc + bias only; C/D layout col=lane&15, row=(lane>>4)*4+j ----
    const int colq = lane & 15, rq = lane >> 4;
    float bcol[4];
    #pragma unroll
    for (int ni = 0; ni < 4; ++ni) bcol[ni] = bias[n0 + wcn * 64 + ni * 16 + colq];
    #pragma unroll
    for (int mi = 0; mi < 8; ++mi) {
        #pragma unroll
        for (int j = 0; j < 4; ++j) {
            const int row = m0 + wr * 128 + mi * 16 + rq * 4 + j;
            #pragma unroll
            for (int ni = 0; ni < 4; ++ni) {
                const int col = n0 + wcn * 64 + ni * 16 + colq;
                out[(size_t)row * O_DIM + col] = acc[mi][ni][j] + bcol[ni];
            }
        }
    }
}

extern "C" void kernel_launch(void* const* d_in, const int* in_sizes, int n_in,
                              void* d_out, int out_size, void* d_ws, size_t ws_size,
                              hipStream_t stream) {
    const float* x        = (const float*)d_in[0];
    const float* W_base   = (const float*)d_in[1];
    const float* b_base   = (const float*)d_in[2];
    const float* A_w      = (const float*)d_in[3];
    const float* B_w      = (const float*)d_in[4];
    const float* router_w = (const float*)d_in[5];
    const float* cores    = (const float*)d_in[6];
    float* out = (float*)d_out;

    char* ws = (char*)d_ws;
    unsigned short* xbf = (unsigned short*)ws;                                   // 64 MiB
    unsigned short* wbf = (unsigned short*)(ws + (size_t)M_DIM * D_DIM * 2);     // 32 MiB
    char* p = ws + (size_t)M_DIM * D_DIM * 2 + (size_t)O_DIM * D_DIM * 2;
    unsigned short* mixbf = (unsigned short*)p;                                  // 512 KiB
    unsigned short* bwbf  = (unsigned short*)(p + (size_t)M_DIM * 32 * 2);       // 256 KiB
    float* ypart = (float*)(p + (size_t)M_DIM * 32 * 2 + (size_t)O_DIM * 32 * 2);  // 6 MiB

    convert_bf16_kernel<<<2048, 256, 0, stream>>>(W_base, wbf, (O_DIM * D_DIM) / 4);
    bwbf_kernel<<<O_DIM / 256, 256, 0, stream>>>(B_w, bwbf);
    partial_mixed_kernel<<<dim3(256, 8), 256, 0, stream>>>(x, A_w, router_w, xbf, ypart);
    finalize_mixed_kernel<<<64, 128, 0, stream>>>(ypart, cores, mixbf);
    gemm_kernel<<<512, 512, 0, stream>>>(xbf, wbf, b_base, mixbf, bwbf, out);
}